// Round 6
// baseline (667.800 us; speedup 1.0000x reference)
//
#include <hip/hip_runtime.h>

#define NSAMP 400000
#define NBLK  1563   // energy grid: ceil(400000/256)
#define NBLKP 782    // pass1 grid: ceil(400000/512), 2 samples/thread

// ---- workspace layout (bytes) ----
// 0    : double acc[8][48]  8 contention-spread copies
// 3072 : unsigned cnt
// 3584 : float  P[10]
// 4096 : float  Gm[256]
// 5120 : float  gv[16]
// 5184 : float  bb[1]
// 8192 : float4 zbuf[NSAMP]

__device__ __forceinline__ float ftanh(float x) {
    float e = __expf(2.0f * x);
    return 1.0f - __fdividef(2.0f, e + 1.0f);
}

__global__ __launch_bounds__(256) void prep_kernel(const float* __restrict__ dw3,
                                                   const float* __restrict__ db3,
                                                   float* __restrict__ Gm,
                                                   float* __restrict__ gv,
                                                   float* __restrict__ bb) {
    __shared__ float sw3[2048];   // 16 x 128
    __shared__ float sb3[128];
    int t = threadIdx.x;
    for (int k = t; k < 2048; k += 256) sw3[k] = dw3[k];
    if (t < 128) sb3[t] = db3[t];
    __syncthreads();
    int a = t >> 4, b = t & 15;
    float s = 0.f;
    for (int j = 0; j < 128; ++j) s = fmaf(sw3[a * 128 + j], sw3[b * 128 + j], s);
    Gm[t] = s;
    if (t < 16) {
        float sg = 0.f;
        for (int j = 0; j < 128; ++j) sg = fmaf(sw3[t * 128 + j], sb3[j], sg);
        gv[t] = sg;
    }
    if (t == 0) {
        float sbv = 0.f;
        for (int j = 0; j < 128; ++j) sbv = fmaf(sb3[j], sb3[j], sbv);
        *bb = sbv;
    }
}

__global__ __launch_bounds__(256, 3) void pass1_kernel(
    const float* __restrict__ x1,
    const float* __restrict__ ew1, const float* __restrict__ eb1,
    const float* __restrict__ ew2, const float* __restrict__ eb2,
    const float* __restrict__ ew3, const float* __restrict__ eb3,
    const float* __restrict__ dw1, const float* __restrict__ db1,
    const float* __restrict__ dw2, const float* __restrict__ db2,
    const float* __restrict__ dw3, const float* __restrict__ db3,
    const float* __restrict__ tw1, const float* __restrict__ tb1,
    const float* __restrict__ tw2, const float* __restrict__ tb2,
    const float* __restrict__ Gm, const float* __restrict__ gv,
    const float* __restrict__ bbp,
    double* __restrict__ acc, float4* __restrict__ zbuf) {
    // 2 samples per thread: one weight broadcast-read now feeds 2 samples'
    // FMAs -> per-CU LDS-pipe demand (the measured ~90% bottleneck) halves.
    // x1 tile: 512 rows x 8 cols per step, 16 steps, double-buffered,
    // wave-private DMA (wave w owns rows w*128..+127), counted vmcnt(4).
    // Slot map: thread t owns slots 4t..4t+3 (row 2t: j=0,1 / row 2t+1:
    // j=2,3), physical = 4t + (j ^ ((t>>1)&3)) -> conflict-free b128 reads.
    __shared__ float4 lbuf[2048];                // 2 x 1024 slots = 32 KiB
    __shared__ float sPart[4][41];
    __shared__ __align__(16) float sEw1[2048];   // [j][k] 128x16
    __shared__ __align__(16) float sDw3[2048];   // [q][j] 16x128
    __shared__ __align__(16) float sGm[256];
    __shared__ __align__(16) float sDb3[128];
    __shared__ __align__(16) float sEw2[128];    // [k][m] 16x8
    __shared__ __align__(16) float sDw2[128];    // [p][q] 8x16
    __shared__ __align__(16) float sTw1[24];     // [d][p] 3x8
    __shared__ __align__(16) float sTw2[32];     // [p][k] 8x4
    __shared__ float sGv[16], sEb1[16], sDb2[16];
    __shared__ float sEb2[8], sEw3[8], sDw1[8], sDb1[8], sTb1[8];
    __shared__ float sTb2[4];
    __shared__ float sBb, sEb3;

    int t = threadIdx.x;
    int bbase = blockIdx.x * 512;
    int ia = bbase + 2 * t, ib = ia + 1;
    bool act_a = (ia < NSAMP), act_b = (ib < NSAMP);
    int w = t >> 6, lane = t & 63;
    int sw2 = (t >> 1) & 3;
    const float4* x1f4 = (const float4*)x1;

    // per-lane DMA source pointers (advance 2 float4 = 8 floats per step)
    const float4* p[4];
#pragma unroll
    for (int c = 0; c < 4; ++c) {
        int S = w * 256 + c * 64 + lane;         // physical slot 0..1023
        int to = S >> 2, jp = S & 3;
        int j = jp ^ ((to >> 1) & 3);            // logical j
        int row = 2 * to + (j >> 1), q = j & 1;
        int grow = bbase + row;
        if (grow >= NSAMP) grow = NSAMP - 1;     // clamp tail (discarded)
        p[c] = x1f4 + (size_t)grow * 32 + q;
    }
    // stage step 0 -> buffer 0
#pragma unroll
    for (int c = 0; c < 4; ++c) {
        __builtin_amdgcn_global_load_lds(
            (const __attribute__((address_space(1))) void*)p[c],
            (__attribute__((address_space(3))) void*)(lbuf + (w * 4 + c) * 64),
            16, 0, 0);
        p[c] += 2;
    }

    // cooperative weight preload (coalesced)
    for (int k = t; k < 2048; k += 256) { sEw1[k] = ew1[k]; sDw3[k] = dw3[k]; }
    sGm[t] = Gm[t];
    if (t < 128) { sDb3[t] = db3[t]; sEw2[t] = ew2[t]; sDw2[t] = dw2[t]; }
    if (t < 16) { sGv[t] = gv[t]; sEb1[t] = eb1[t]; sDb2[t] = db2[t]; }
    if (t < 8) { sEb2[t] = eb2[t]; sEw3[t] = ew3[t]; sDw1[t] = dw1[t];
                 sDb1[t] = db1[t]; sTb1[t] = tb1[t]; }
    if (t < 24) sTw1[t] = tw1[t];
    if (t < 32) sTw2[t] = tw2[t];
    if (t < 4) sTb2[t] = tb2[t];
    if (t == 0) { sBb = *bbp; sEb3 = eb3[0]; }
    __syncthreads();   // weights visible

    const float4* sEw1_4 = (const float4*)sEw1;
    const float4* sDw3_4 = (const float4*)sDw3;
    const float4* sDb3_4 = (const float4*)sDb3;
    const float4* sGm_4  = (const float4*)sGm;
    const float4* sEw2_4 = (const float4*)sEw2;
    const float4* sDw2_4 = (const float4*)sDw2;
    const float4* sTw1_4 = (const float4*)sTw1;
    const float4* sTw2_4 = (const float4*)sTw2;

    float ua[16], va[16], ub[16], vb[16];
#pragma unroll
    for (int k = 0; k < 16; ++k) { ua[k] = 0.f; va[k] = 0.f; ub[k] = 0.f; vb[k] = 0.f; }
    float s2a = 0.f, sba = 0.f, s2b = 0.f, sbb = 0.f;

    auto consume = [&](int s, int bofs) {
        float4 w0 = lbuf[bofs + t * 4 + (0 ^ sw2)];
        float4 w1 = lbuf[bofs + t * 4 + (1 ^ sw2)];
        float4 w2 = lbuf[bofs + t * 4 + (2 ^ sw2)];
        float4 w3 = lbuf[bofs + t * 4 + (3 ^ sw2)];
        float xa[8] = {w0.x, w0.y, w0.z, w0.w, w1.x, w1.y, w1.z, w1.w};
        float xb[8] = {w2.x, w2.y, w2.z, w2.w, w3.x, w3.y, w3.z, w3.w};
        float4 b0 = sDb3_4[s * 2], b1 = sDb3_4[s * 2 + 1];
        float bx[8] = {b0.x, b0.y, b0.z, b0.w, b1.x, b1.y, b1.z, b1.w};
#pragma unroll
        for (int e = 0; e < 8; ++e) {
            s2a = fmaf(xa[e], xa[e], s2a); sba = fmaf(xa[e], bx[e], sba);
            s2b = fmaf(xb[e], xb[e], s2b); sbb = fmaf(xb[e], bx[e], sbb);
        }
#pragma unroll
        for (int e = 0; e < 8; ++e) {
            int jr = s * 8 + e;
#pragma unroll
            for (int kk = 0; kk < 4; ++kk) {
                float4 wv = sEw1_4[jr * 4 + kk];
                ua[kk*4+0] = fmaf(xa[e], wv.x, ua[kk*4+0]);
                ua[kk*4+1] = fmaf(xa[e], wv.y, ua[kk*4+1]);
                ua[kk*4+2] = fmaf(xa[e], wv.z, ua[kk*4+2]);
                ua[kk*4+3] = fmaf(xa[e], wv.w, ua[kk*4+3]);
                ub[kk*4+0] = fmaf(xb[e], wv.x, ub[kk*4+0]);
                ub[kk*4+1] = fmaf(xb[e], wv.y, ub[kk*4+1]);
                ub[kk*4+2] = fmaf(xb[e], wv.z, ub[kk*4+2]);
                ub[kk*4+3] = fmaf(xb[e], wv.w, ub[kk*4+3]);
            }
        }
#pragma unroll
        for (int q = 0; q < 16; ++q) {
            float aa = va[q], ab = vb[q];
#pragma unroll
            for (int ee = 0; ee < 2; ++ee) {
                float4 wv = sDw3_4[q * 32 + s * 2 + ee];
                aa = fmaf(xa[ee*4+0], wv.x, aa); aa = fmaf(xa[ee*4+1], wv.y, aa);
                aa = fmaf(xa[ee*4+2], wv.z, aa); aa = fmaf(xa[ee*4+3], wv.w, aa);
                ab = fmaf(xb[ee*4+0], wv.x, ab); ab = fmaf(xb[ee*4+1], wv.y, ab);
                ab = fmaf(xb[ee*4+2], wv.z, ab); ab = fmaf(xb[ee*4+3], wv.w, ab);
            }
            va[q] = aa; vb[q] = ab;
        }
    };

#pragma unroll 1
    for (int s = 0; s < 15; ++s) {
        int nb = ((s + 1) & 1) * 1024;
#pragma unroll
        for (int c = 0; c < 4; ++c) {
            __builtin_amdgcn_global_load_lds(
                (const __attribute__((address_space(1))) void*)p[c],
                (__attribute__((address_space(3))) void*)(lbuf + nb + (w * 4 + c) * 64),
                16, 0, 0);
            p[c] += 2;
        }
        asm volatile("s_waitcnt vmcnt(4)" ::: "memory");
        __builtin_amdgcn_sched_barrier(0);
        consume(s, (s & 1) * 1024);
    }
    asm volatile("s_waitcnt vmcnt(0)" ::: "memory");
    __builtin_amdgcn_sched_barrier(0);
    consume(15, 1024);

    // per-sample tail (identical math/order to verified R5 tail)
    auto tail = [&](float (&u)[16], float (&v)[16], float s2, float sb,
                    float (&zf)[3], float (&gam)[4], float &euc2) {
        float h1[16];
#pragma unroll
        for (int k = 0; k < 16; ++k) h1[k] = ftanh(u[k] + sEb1[k]);
        float a2m[8];
#pragma unroll
        for (int m = 0; m < 8; ++m) a2m[m] = sEb2[m];
#pragma unroll
        for (int k = 0; k < 16; ++k) {
            float4 r0 = sEw2_4[k * 2], r1 = sEw2_4[k * 2 + 1];
            a2m[0] = fmaf(h1[k], r0.x, a2m[0]); a2m[1] = fmaf(h1[k], r0.y, a2m[1]);
            a2m[2] = fmaf(h1[k], r0.z, a2m[2]); a2m[3] = fmaf(h1[k], r0.w, a2m[3]);
            a2m[4] = fmaf(h1[k], r1.x, a2m[4]); a2m[5] = fmaf(h1[k], r1.y, a2m[5]);
            a2m[6] = fmaf(h1[k], r1.z, a2m[6]); a2m[7] = fmaf(h1[k], r1.w, a2m[7]);
        }
        float h2[8];
#pragma unroll
        for (int m = 0; m < 8; ++m) h2[m] = ftanh(a2m[m]);
        float a3 = sEb3;
#pragma unroll
        for (int m = 0; m < 8; ++m) a3 = fmaf(h2[m], sEw3[m], a3);
        float z1 = ftanh(a3);
        float d1[8];
#pragma unroll
        for (int p2 = 0; p2 < 8; ++p2) d1[p2] = ftanh(fmaf(z1, sDw1[p2], sDb1[p2]));
        float a2q[16];
#pragma unroll
        for (int q = 0; q < 16; ++q) a2q[q] = sDb2[q];
#pragma unroll
        for (int p2 = 0; p2 < 8; ++p2) {
#pragma unroll
            for (int q4 = 0; q4 < 4; ++q4) {
                float4 r = sDw2_4[p2 * 4 + q4];
                a2q[q4*4+0] = fmaf(d1[p2], r.x, a2q[q4*4+0]);
                a2q[q4*4+1] = fmaf(d1[p2], r.y, a2q[q4*4+1]);
                a2q[q4*4+2] = fmaf(d1[p2], r.z, a2q[q4*4+2]);
                a2q[q4*4+3] = fmaf(d1[p2], r.w, a2q[q4*4+3]);
            }
        }
        float d2[16];
#pragma unroll
        for (int q = 0; q < 16; ++q) d2[q] = ftanh(a2q[q]);
        float dot = sb;
#pragma unroll
        for (int q = 0; q < 16; ++q) dot = fmaf(d2[q], v[q], dot);
        float n2 = sBb;
#pragma unroll
        for (int a = 0; a < 16; ++a) {
            float ra = 2.0f * sGv[a];
#pragma unroll
            for (int b4 = 0; b4 < 4; ++b4) {
                float4 g = sGm_4[a * 4 + b4];
                ra = fmaf(g.x, d2[b4*4+0], ra);
                ra = fmaf(g.y, d2[b4*4+1], ra);
                ra = fmaf(g.z, d2[b4*4+2], ra);
                ra = fmaf(g.w, d2[b4*4+3], ra);
            }
            n2 = fmaf(d2[a], ra, n2);
        }
        n2 = fmaxf(n2, 1e-20f);
        euc2 = fmaxf(s2 - 2.0f * dot + n2, 0.f);
        float deuc = sqrtf(euc2);
        float dcos = dot * rsqrtf(s2 * n2);
        zf[0] = z1; zf[1] = dcos; zf[2] = deuc;
        float e1a[8];
#pragma unroll
        for (int p2 = 0; p2 < 8; ++p2) e1a[p2] = sTb1[p2];
#pragma unroll
        for (int d = 0; d < 3; ++d) {
            float4 r0 = sTw1_4[d * 2], r1 = sTw1_4[d * 2 + 1];
            e1a[0] = fmaf(zf[d], r0.x, e1a[0]); e1a[1] = fmaf(zf[d], r0.y, e1a[1]);
            e1a[2] = fmaf(zf[d], r0.z, e1a[2]); e1a[3] = fmaf(zf[d], r0.w, e1a[3]);
            e1a[4] = fmaf(zf[d], r1.x, e1a[4]); e1a[5] = fmaf(zf[d], r1.y, e1a[5]);
            e1a[6] = fmaf(zf[d], r1.z, e1a[6]); e1a[7] = fmaf(zf[d], r1.w, e1a[7]);
        }
        float e1[8];
#pragma unroll
        for (int p2 = 0; p2 < 8; ++p2) e1[p2] = ftanh(e1a[p2]);
        float lg[4];
#pragma unroll
        for (int k = 0; k < 4; ++k) lg[k] = sTb2[k];
#pragma unroll
        for (int p2 = 0; p2 < 8; ++p2) {
            float4 r = sTw2_4[p2];
            lg[0] = fmaf(e1[p2], r.x, lg[0]); lg[1] = fmaf(e1[p2], r.y, lg[1]);
            lg[2] = fmaf(e1[p2], r.z, lg[2]); lg[3] = fmaf(e1[p2], r.w, lg[3]);
        }
        float mx = fmaxf(fmaxf(lg[0], lg[1]), fmaxf(lg[2], lg[3]));
        float ex[4]; float se = 0.f;
#pragma unroll
        for (int k = 0; k < 4; ++k) { ex[k] = __expf(lg[k] - mx); se += ex[k]; }
        float inv = __fdividef(1.0f, se);
#pragma unroll
        for (int k = 0; k < 4; ++k) gam[k] = ex[k] * inv;
    };

    float zfa[3], gama[4], euc2a;
    float zfb[3], gamb[4], euc2b;
    tail(ua, va, s2a, sba, zfa, gama, euc2a);
    tail(ub, vb, s2b, sbb, zfb, gamb, euc2b);

    if (act_a) zbuf[ia] = make_float4(zfa[0], zfa[1], zfa[2], 0.f);
    if (act_b) zbuf[ib] = make_float4(zfb[0], zfb[1], zfb[2], 0.f);
    if (!act_a) { gama[0] = gama[1] = gama[2] = gama[3] = 0.f; euc2a = 0.f; }
    if (!act_b) { gamb[0] = gamb[1] = gamb[2] = gamb[3] = 0.f; euc2b = 0.f; }

    // block reduction of 41 moment values (pair pre-summed in-thread)
    int rlane = threadIdx.x & 63;
    int wid = threadIdx.x >> 6;

#define REDUCE_STORE(T, VAL) { float _v = (VAL);                          \
        _v += __shfl_down(_v, 32); _v += __shfl_down(_v, 16);             \
        _v += __shfl_down(_v, 8);  _v += __shfl_down(_v, 4);              \
        _v += __shfl_down(_v, 2);  _v += __shfl_down(_v, 1);              \
        if (rlane == 0) sPart[wid][T] = _v; }

#pragma unroll
    for (int k = 0; k < 4; ++k) REDUCE_STORE(k, gama[k] + gamb[k]);
#pragma unroll
    for (int k = 0; k < 4; ++k) {
#pragma unroll
        for (int d = 0; d < 3; ++d)
            REDUCE_STORE(4 + k * 3 + d, gama[k] * zfa[d] + gamb[k] * zfb[d]);
    }
#pragma unroll
    for (int k = 0; k < 4; ++k) {
        REDUCE_STORE(16 + k * 6 + 0, gama[k]*zfa[0]*zfa[0] + gamb[k]*zfb[0]*zfb[0]);
        REDUCE_STORE(16 + k * 6 + 1, gama[k]*zfa[0]*zfa[1] + gamb[k]*zfb[0]*zfb[1]);
        REDUCE_STORE(16 + k * 6 + 2, gama[k]*zfa[0]*zfa[2] + gamb[k]*zfb[0]*zfb[2]);
        REDUCE_STORE(16 + k * 6 + 3, gama[k]*zfa[1]*zfa[1] + gamb[k]*zfb[1]*zfb[1]);
        REDUCE_STORE(16 + k * 6 + 4, gama[k]*zfa[1]*zfa[2] + gamb[k]*zfb[1]*zfb[2]);
        REDUCE_STORE(16 + k * 6 + 5, gama[k]*zfa[2]*zfa[2] + gamb[k]*zfb[2]*zfb[2]);
    }
    REDUCE_STORE(40, euc2a + euc2b);
#undef REDUCE_STORE

    __syncthreads();
    if (threadIdx.x < 41) {
        double s = (double)sPart[0][threadIdx.x] + (double)sPart[1][threadIdx.x]
                 + (double)sPart[2][threadIdx.x] + (double)sPart[3][threadIdx.x];
        double* accs = acc + (size_t)(blockIdx.x & 7) * 48;
        unsafeAtomicAdd(&accs[threadIdx.x], s);
    }
}

__global__ void gmm_kernel(double* __restrict__ acc, float* __restrict__ P) {
    if (threadIdx.x != 0 || blockIdx.x != 0) return;
    for (int j = 0; j < 42; ++j) {
        double s = acc[j];
        for (int c = 1; c < 8; ++c) s += acc[c * 48 + j];
        acc[j] = s;
    }
    double M[6] = {0, 0, 0, 0, 0, 0}, bv[3] = {0, 0, 0}, A = 0.0, loss3 = 0.0;
    const double TWO_PI = 6.283185307179586;
    for (int k = 0; k < 4; ++k) {
        double g = acc[k];
        double phi = g / (double)NSAMP;
        double mu0 = acc[4 + k * 3 + 0] / g;
        double mu1 = acc[4 + k * 3 + 1] / g;
        double mu2 = acc[4 + k * 3 + 2] / g;
        double S00 = acc[16 + k * 6 + 0] / g - mu0 * mu0;
        double S01 = acc[16 + k * 6 + 1] / g - mu0 * mu1;
        double S02 = acc[16 + k * 6 + 2] / g - mu0 * mu2;
        double S11 = acc[16 + k * 6 + 3] / g - mu1 * mu1;
        double S12 = acc[16 + k * 6 + 4] / g - mu1 * mu2;
        double S22 = acc[16 + k * 6 + 5] / g - mu2 * mu2;
        double c00 = S11 * S22 - S12 * S12;
        double c01 = S02 * S12 - S01 * S22;
        double c02 = S01 * S12 - S02 * S11;
        double det = S00 * c00 + S01 * c01 + S02 * c02;
        double id = 1.0 / det;
        double I00 = c00 * id, I01 = c01 * id, I02 = c02 * id;
        double I11 = (S00 * S22 - S02 * S02) * id;
        double I12 = (S01 * S02 - S00 * S12) * id;
        double I22 = (S00 * S11 - S01 * S01) * id;
        M[0] += I00; M[1] += I01; M[2] += I02; M[3] += I11; M[4] += I12; M[5] += I22;
        double b0 = I00 * mu0 + I01 * mu1 + I02 * mu2;
        double b1 = I01 * mu0 + I11 * mu1 + I12 * mu2;
        double b2 = I02 * mu0 + I12 * mu1 + I22 * mu2;
        bv[0] += b0; bv[1] += b1; bv[2] += b2;
        double quad = mu0 * b0 + mu1 * b1 + mu2 * b2;
        A += -log(phi) + 0.5 * log(TWO_PI * TWO_PI * TWO_PI * det) + 0.5 * quad;
        loss3 += 1e-4 * (1.0 / S00 + 1.0 / S11 + 1.0 / S22);
    }
    P[0] = (float)M[0]; P[1] = (float)M[1]; P[2] = (float)M[2];
    P[3] = (float)M[3]; P[4] = (float)M[4]; P[5] = (float)M[5];
    P[6] = (float)bv[0]; P[7] = (float)bv[1]; P[8] = (float)bv[2];
    P[9] = (float)A;
    acc[42] = acc[40] / (double)NSAMP + loss3;   // loss1 + loss3
}

__global__ __launch_bounds__(256) void energy_kernel(const float4* __restrict__ zbuf,
                                                     const float* __restrict__ P,
                                                     double* __restrict__ acc,
                                                     unsigned* __restrict__ cnt,
                                                     float* __restrict__ out) {
    int i = blockIdx.x * 256 + threadIdx.x;
    float e = 0.f;
    if (i < NSAMP) {
        float4 z4 = zbuf[i];
        float z0 = z4.x, z1 = z4.y, z2 = z4.z;
        float q = P[0] * z0 * z0 + P[3] * z1 * z1 + P[5] * z2 * z2
                + 2.f * (P[1] * z0 * z1 + P[2] * z0 * z2 + P[4] * z1 * z2);
        e = P[9] + 0.5f * q - (P[6] * z0 + P[7] * z1 + P[8] * z2);
        out[i] = e;
    }
    float s = e;
    s += __shfl_down(s, 32); s += __shfl_down(s, 16); s += __shfl_down(s, 8);
    s += __shfl_down(s, 4);  s += __shfl_down(s, 2);  s += __shfl_down(s, 1);
    __shared__ float sE[4];
    if ((threadIdx.x & 63) == 0) sE[threadIdx.x >> 6] = s;
    __syncthreads();
    if (threadIdx.x == 0) {
        double t = (double)sE[0] + (double)sE[1] + (double)sE[2] + (double)sE[3];
        double* accs = acc + (size_t)(blockIdx.x & 7) * 48;
        unsafeAtomicAdd(&accs[41], t);
        __threadfence();
        unsigned old = atomicAdd(cnt, 1u);
        if (old == (unsigned)(NBLK - 1)) {
            double tot = 0.0;
            for (int c = 0; c < 8; ++c)
                tot += unsafeAtomicAdd(&acc[c * 48 + 41], 0.0);
            out[NSAMP] = (float)(acc[42] + 0.01 * tot / (double)NSAMP);
        }
    }
}

extern "C" void kernel_launch(void* const* d_in, const int* in_sizes, int n_in,
                              void* d_out, int out_size, void* d_ws, size_t ws_size,
                              hipStream_t stream) {
    const float* x1  = (const float*)d_in[0];
    const float* ew1 = (const float*)d_in[1];
    const float* eb1 = (const float*)d_in[2];
    const float* ew2 = (const float*)d_in[3];
    const float* eb2 = (const float*)d_in[4];
    const float* ew3 = (const float*)d_in[5];
    const float* eb3 = (const float*)d_in[6];
    const float* dw1 = (const float*)d_in[7];
    const float* db1 = (const float*)d_in[8];
    const float* dw2 = (const float*)d_in[9];
    const float* db2 = (const float*)d_in[10];
    const float* dw3 = (const float*)d_in[11];
    const float* db3 = (const float*)d_in[12];
    const float* tw1 = (const float*)d_in[13];
    const float* tb1 = (const float*)d_in[14];
    const float* tw2 = (const float*)d_in[15];
    const float* tb2 = (const float*)d_in[16];
    float* out = (float*)d_out;
    char* ws = (char*)d_ws;
    double* acc   = (double*)ws;                 // 8 copies x 48 doubles
    unsigned* cnt = (unsigned*)(ws + 3072);
    float* P    = (float*)(ws + 3584);
    float* Gm   = (float*)(ws + 4096);
    float* gv   = (float*)(ws + 5120);
    float* bb   = (float*)(ws + 5184);
    float4* zb  = (float4*)(ws + 8192);

    hipMemsetAsync(d_ws, 0, 3584, stream);
    prep_kernel<<<1, 256, 0, stream>>>(dw3, db3, Gm, gv, bb);
    pass1_kernel<<<NBLKP, 256, 0, stream>>>(x1, ew1, eb1, ew2, eb2, ew3, eb3,
                                            dw1, db1, dw2, db2, dw3, db3,
                                            tw1, tb1, tw2, tb2, Gm, gv, bb, acc, zb);
    gmm_kernel<<<1, 64, 0, stream>>>(acc, P);
    energy_kernel<<<NBLK, 256, 0, stream>>>(zb, P, acc, cnt, out);
}

// Round 7
// 512.232 us; speedup vs baseline: 1.3037x; 1.3037x over previous
//
#include <hip/hip_runtime.h>

#define NSAMP 400000
#define NBLK  1563   // energy grid: ceil(400000/256)
#define NBLKP 782    // pass1 grid: ceil(400000/512), 2 samples/thread

// ---- workspace layout (bytes) ----
// 0    : double acc[8][48]  8 contention-spread copies
// 3072 : unsigned cnt
// 3584 : float  P[10]
// 4096 : float  Gm[256]
// 5120 : float  gv[16]
// 5184 : float  bb[1]
// 8192 : float4 zbuf[NSAMP]

__device__ __forceinline__ float ftanh(float x) {
    float e = __expf(2.0f * x);
    return 1.0f - __fdividef(2.0f, e + 1.0f);
}

__global__ __launch_bounds__(256) void prep_kernel(const float* __restrict__ dw3,
                                                   const float* __restrict__ db3,
                                                   float* __restrict__ Gm,
                                                   float* __restrict__ gv,
                                                   float* __restrict__ bb) {
    __shared__ float sw3[2048];   // 16 x 128
    __shared__ float sb3[128];
    int t = threadIdx.x;
    for (int k = t; k < 2048; k += 256) sw3[k] = dw3[k];
    if (t < 128) sb3[t] = db3[t];
    __syncthreads();
    int a = t >> 4, b = t & 15;
    float s = 0.f;
    for (int j = 0; j < 128; ++j) s = fmaf(sw3[a * 128 + j], sw3[b * 128 + j], s);
    Gm[t] = s;
    if (t < 16) {
        float sg = 0.f;
        for (int j = 0; j < 128; ++j) sg = fmaf(sw3[t * 128 + j], sb3[j], sg);
        gv[t] = sg;
    }
    if (t == 0) {
        float sbv = 0.f;
        for (int j = 0; j < 128; ++j) sbv = fmaf(sb3[j], sb3[j], sbv);
        *bb = sbv;
    }
}

// NOTE: plain __launch_bounds__(256). R6's (256,3) made the compiler cap
// VGPR at 84 -> 443 MB/dispatch scratch-spill writes (the whole regression).
// R5's plain attribute gave spill-free allocation; 2-sample state needs
// ~150 VGPR which still sustains 3 waves/SIMD (LDS caps at 3 blocks/CU).
__global__ __launch_bounds__(256) void pass1_kernel(
    const float* __restrict__ x1,
    const float* __restrict__ ew1, const float* __restrict__ eb1,
    const float* __restrict__ ew2, const float* __restrict__ eb2,
    const float* __restrict__ ew3, const float* __restrict__ eb3,
    const float* __restrict__ dw1, const float* __restrict__ db1,
    const float* __restrict__ dw2, const float* __restrict__ db2,
    const float* __restrict__ dw3, const float* __restrict__ db3,
    const float* __restrict__ tw1, const float* __restrict__ tb1,
    const float* __restrict__ tw2, const float* __restrict__ tb2,
    const float* __restrict__ Gm, const float* __restrict__ gv,
    const float* __restrict__ bbp,
    double* __restrict__ acc, float4* __restrict__ zbuf) {
    // 2 samples per thread: one weight broadcast-read feeds 2 samples' FMAs
    // -> per-CU LDS-pipe demand (measured ~90% at R5) halves.
    // x1 tile: 512 rows x 8 cols per step, 16 steps, double-buffered,
    // wave-private DMA (wave w owns rows w*128..+127), counted vmcnt(4).
    __shared__ float4 lbuf[2048];                // 2 x 1024 slots = 32 KiB
    __shared__ float sPart[4][41];
    __shared__ __align__(16) float sEw1[2048];   // [j][k] 128x16
    __shared__ __align__(16) float sDw3[2048];   // [q][j] 16x128
    __shared__ __align__(16) float sGm[256];
    __shared__ __align__(16) float sDb3[128];
    __shared__ __align__(16) float sEw2[128];    // [k][m] 16x8
    __shared__ __align__(16) float sDw2[128];    // [p][q] 8x16
    __shared__ __align__(16) float sTw1[24];     // [d][p] 3x8
    __shared__ __align__(16) float sTw2[32];     // [p][k] 8x4
    __shared__ float sGv[16], sEb1[16], sDb2[16];
    __shared__ float sEb2[8], sEw3[8], sDw1[8], sDb1[8], sTb1[8];
    __shared__ float sTb2[4];
    __shared__ float sBb, sEb3;

    int t = threadIdx.x;
    int bbase = blockIdx.x * 512;
    int ia = bbase + 2 * t, ib = ia + 1;
    bool act_a = (ia < NSAMP), act_b = (ib < NSAMP);
    int w = t >> 6, lane = t & 63;
    int sw2 = (t >> 1) & 3;
    const float4* x1f4 = (const float4*)x1;

    // per-lane DMA source pointers (advance 2 float4 = 8 floats per step)
    const float4* p[4];
#pragma unroll
    for (int c = 0; c < 4; ++c) {
        int S = w * 256 + c * 64 + lane;         // physical slot 0..1023
        int to = S >> 2, jp = S & 3;
        int j = jp ^ ((to >> 1) & 3);            // logical j
        int row = 2 * to + (j >> 1), q = j & 1;
        int grow = bbase + row;
        if (grow >= NSAMP) grow = NSAMP - 1;     // clamp tail (discarded)
        p[c] = x1f4 + (size_t)grow * 32 + q;
    }
    // stage step 0 -> buffer 0
#pragma unroll
    for (int c = 0; c < 4; ++c) {
        __builtin_amdgcn_global_load_lds(
            (const __attribute__((address_space(1))) void*)p[c],
            (__attribute__((address_space(3))) void*)(lbuf + (w * 4 + c) * 64),
            16, 0, 0);
        p[c] += 2;
    }

    // cooperative weight preload (coalesced)
    for (int k = t; k < 2048; k += 256) { sEw1[k] = ew1[k]; sDw3[k] = dw3[k]; }
    sGm[t] = Gm[t];
    if (t < 128) { sDb3[t] = db3[t]; sEw2[t] = ew2[t]; sDw2[t] = dw2[t]; }
    if (t < 16) { sGv[t] = gv[t]; sEb1[t] = eb1[t]; sDb2[t] = db2[t]; }
    if (t < 8) { sEb2[t] = eb2[t]; sEw3[t] = ew3[t]; sDw1[t] = dw1[t];
                 sDb1[t] = db1[t]; sTb1[t] = tb1[t]; }
    if (t < 24) sTw1[t] = tw1[t];
    if (t < 32) sTw2[t] = tw2[t];
    if (t < 4) sTb2[t] = tb2[t];
    if (t == 0) { sBb = *bbp; sEb3 = eb3[0]; }
    __syncthreads();   // weights visible

    const float4* sEw1_4 = (const float4*)sEw1;
    const float4* sDw3_4 = (const float4*)sDw3;
    const float4* sDb3_4 = (const float4*)sDb3;
    const float4* sGm_4  = (const float4*)sGm;
    const float4* sEw2_4 = (const float4*)sEw2;
    const float4* sDw2_4 = (const float4*)sDw2;
    const float4* sTw1_4 = (const float4*)sTw1;
    const float4* sTw2_4 = (const float4*)sTw2;

    float ua[16], va[16], ub[16], vb[16];
#pragma unroll
    for (int k = 0; k < 16; ++k) { ua[k] = 0.f; va[k] = 0.f; ub[k] = 0.f; vb[k] = 0.f; }
    float s2a = 0.f, sba = 0.f, s2b = 0.f, sbb = 0.f;

    auto consume = [&](int s, int bofs) {
        float4 w0 = lbuf[bofs + t * 4 + (0 ^ sw2)];
        float4 w1 = lbuf[bofs + t * 4 + (1 ^ sw2)];
        float4 w2 = lbuf[bofs + t * 4 + (2 ^ sw2)];
        float4 w3 = lbuf[bofs + t * 4 + (3 ^ sw2)];
        float xa[8] = {w0.x, w0.y, w0.z, w0.w, w1.x, w1.y, w1.z, w1.w};
        float xb[8] = {w2.x, w2.y, w2.z, w2.w, w3.x, w3.y, w3.z, w3.w};
        float4 b0 = sDb3_4[s * 2], b1 = sDb3_4[s * 2 + 1];
        float bx[8] = {b0.x, b0.y, b0.z, b0.w, b1.x, b1.y, b1.z, b1.w};
#pragma unroll
        for (int e = 0; e < 8; ++e) {
            s2a = fmaf(xa[e], xa[e], s2a); sba = fmaf(xa[e], bx[e], sba);
            s2b = fmaf(xb[e], xb[e], s2b); sbb = fmaf(xb[e], bx[e], sbb);
        }
#pragma unroll
        for (int e = 0; e < 8; ++e) {
            int jr = s * 8 + e;
#pragma unroll
            for (int kk = 0; kk < 4; ++kk) {
                float4 wv = sEw1_4[jr * 4 + kk];
                ua[kk*4+0] = fmaf(xa[e], wv.x, ua[kk*4+0]);
                ua[kk*4+1] = fmaf(xa[e], wv.y, ua[kk*4+1]);
                ua[kk*4+2] = fmaf(xa[e], wv.z, ua[kk*4+2]);
                ua[kk*4+3] = fmaf(xa[e], wv.w, ua[kk*4+3]);
                ub[kk*4+0] = fmaf(xb[e], wv.x, ub[kk*4+0]);
                ub[kk*4+1] = fmaf(xb[e], wv.y, ub[kk*4+1]);
                ub[kk*4+2] = fmaf(xb[e], wv.z, ub[kk*4+2]);
                ub[kk*4+3] = fmaf(xb[e], wv.w, ub[kk*4+3]);
            }
        }
#pragma unroll
        for (int q = 0; q < 16; ++q) {
            float aa = va[q], ab = vb[q];
#pragma unroll
            for (int ee = 0; ee < 2; ++ee) {
                float4 wv = sDw3_4[q * 32 + s * 2 + ee];
                aa = fmaf(xa[ee*4+0], wv.x, aa); aa = fmaf(xa[ee*4+1], wv.y, aa);
                aa = fmaf(xa[ee*4+2], wv.z, aa); aa = fmaf(xa[ee*4+3], wv.w, aa);
                ab = fmaf(xb[ee*4+0], wv.x, ab); ab = fmaf(xb[ee*4+1], wv.y, ab);
                ab = fmaf(xb[ee*4+2], wv.z, ab); ab = fmaf(xb[ee*4+3], wv.w, ab);
            }
            va[q] = aa; vb[q] = ab;
        }
    };

#pragma unroll 1
    for (int s = 0; s < 15; ++s) {
        int nb = ((s + 1) & 1) * 1024;
#pragma unroll
        for (int c = 0; c < 4; ++c) {
            __builtin_amdgcn_global_load_lds(
                (const __attribute__((address_space(1))) void*)p[c],
                (__attribute__((address_space(3))) void*)(lbuf + nb + (w * 4 + c) * 64),
                16, 0, 0);
            p[c] += 2;
        }
        asm volatile("s_waitcnt vmcnt(4)" ::: "memory");
        __builtin_amdgcn_sched_barrier(0);
        consume(s, (s & 1) * 1024);
    }
    asm volatile("s_waitcnt vmcnt(0)" ::: "memory");
    __builtin_amdgcn_sched_barrier(0);
    consume(15, 1024);

    // per-sample tail (identical math/order to verified R5/R6 tail)
    auto tail = [&](float (&u)[16], float (&v)[16], float s2, float sb,
                    float (&zf)[3], float (&gam)[4], float &euc2) {
        float h1[16];
#pragma unroll
        for (int k = 0; k < 16; ++k) h1[k] = ftanh(u[k] + sEb1[k]);
        float a2m[8];
#pragma unroll
        for (int m = 0; m < 8; ++m) a2m[m] = sEb2[m];
#pragma unroll
        for (int k = 0; k < 16; ++k) {
            float4 r0 = sEw2_4[k * 2], r1 = sEw2_4[k * 2 + 1];
            a2m[0] = fmaf(h1[k], r0.x, a2m[0]); a2m[1] = fmaf(h1[k], r0.y, a2m[1]);
            a2m[2] = fmaf(h1[k], r0.z, a2m[2]); a2m[3] = fmaf(h1[k], r0.w, a2m[3]);
            a2m[4] = fmaf(h1[k], r1.x, a2m[4]); a2m[5] = fmaf(h1[k], r1.y, a2m[5]);
            a2m[6] = fmaf(h1[k], r1.z, a2m[6]); a2m[7] = fmaf(h1[k], r1.w, a2m[7]);
        }
        float h2[8];
#pragma unroll
        for (int m = 0; m < 8; ++m) h2[m] = ftanh(a2m[m]);
        float a3 = sEb3;
#pragma unroll
        for (int m = 0; m < 8; ++m) a3 = fmaf(h2[m], sEw3[m], a3);
        float z1 = ftanh(a3);
        float d1[8];
#pragma unroll
        for (int p2 = 0; p2 < 8; ++p2) d1[p2] = ftanh(fmaf(z1, sDw1[p2], sDb1[p2]));
        float a2q[16];
#pragma unroll
        for (int q = 0; q < 16; ++q) a2q[q] = sDb2[q];
#pragma unroll
        for (int p2 = 0; p2 < 8; ++p2) {
#pragma unroll
            for (int q4 = 0; q4 < 4; ++q4) {
                float4 r = sDw2_4[p2 * 4 + q4];
                a2q[q4*4+0] = fmaf(d1[p2], r.x, a2q[q4*4+0]);
                a2q[q4*4+1] = fmaf(d1[p2], r.y, a2q[q4*4+1]);
                a2q[q4*4+2] = fmaf(d1[p2], r.z, a2q[q4*4+2]);
                a2q[q4*4+3] = fmaf(d1[p2], r.w, a2q[q4*4+3]);
            }
        }
        float d2[16];
#pragma unroll
        for (int q = 0; q < 16; ++q) d2[q] = ftanh(a2q[q]);
        float dot = sb;
#pragma unroll
        for (int q = 0; q < 16; ++q) dot = fmaf(d2[q], v[q], dot);
        float n2 = sBb;
#pragma unroll
        for (int a = 0; a < 16; ++a) {
            float ra = 2.0f * sGv[a];
#pragma unroll
            for (int b4 = 0; b4 < 4; ++b4) {
                float4 g = sGm_4[a * 4 + b4];
                ra = fmaf(g.x, d2[b4*4+0], ra);
                ra = fmaf(g.y, d2[b4*4+1], ra);
                ra = fmaf(g.z, d2[b4*4+2], ra);
                ra = fmaf(g.w, d2[b4*4+3], ra);
            }
            n2 = fmaf(d2[a], ra, n2);
        }
        n2 = fmaxf(n2, 1e-20f);
        euc2 = fmaxf(s2 - 2.0f * dot + n2, 0.f);
        float deuc = sqrtf(euc2);
        float dcos = dot * rsqrtf(s2 * n2);
        zf[0] = z1; zf[1] = dcos; zf[2] = deuc;
        float e1a[8];
#pragma unroll
        for (int p2 = 0; p2 < 8; ++p2) e1a[p2] = sTb1[p2];
#pragma unroll
        for (int d = 0; d < 3; ++d) {
            float4 r0 = sTw1_4[d * 2], r1 = sTw1_4[d * 2 + 1];
            e1a[0] = fmaf(zf[d], r0.x, e1a[0]); e1a[1] = fmaf(zf[d], r0.y, e1a[1]);
            e1a[2] = fmaf(zf[d], r0.z, e1a[2]); e1a[3] = fmaf(zf[d], r0.w, e1a[3]);
            e1a[4] = fmaf(zf[d], r1.x, e1a[4]); e1a[5] = fmaf(zf[d], r1.y, e1a[5]);
            e1a[6] = fmaf(zf[d], r1.z, e1a[6]); e1a[7] = fmaf(zf[d], r1.w, e1a[7]);
        }
        float e1[8];
#pragma unroll
        for (int p2 = 0; p2 < 8; ++p2) e1[p2] = ftanh(e1a[p2]);
        float lg[4];
#pragma unroll
        for (int k = 0; k < 4; ++k) lg[k] = sTb2[k];
#pragma unroll
        for (int p2 = 0; p2 < 8; ++p2) {
            float4 r = sTw2_4[p2];
            lg[0] = fmaf(e1[p2], r.x, lg[0]); lg[1] = fmaf(e1[p2], r.y, lg[1]);
            lg[2] = fmaf(e1[p2], r.z, lg[2]); lg[3] = fmaf(e1[p2], r.w, lg[3]);
        }
        float mx = fmaxf(fmaxf(lg[0], lg[1]), fmaxf(lg[2], lg[3]));
        float ex[4]; float se = 0.f;
#pragma unroll
        for (int k = 0; k < 4; ++k) { ex[k] = __expf(lg[k] - mx); se += ex[k]; }
        float inv = __fdividef(1.0f, se);
#pragma unroll
        for (int k = 0; k < 4; ++k) gam[k] = ex[k] * inv;
    };

    float zfa[3], gama[4], euc2a;
    float zfb[3], gamb[4], euc2b;
    tail(ua, va, s2a, sba, zfa, gama, euc2a);
    tail(ub, vb, s2b, sbb, zfb, gamb, euc2b);

    if (act_a) zbuf[ia] = make_float4(zfa[0], zfa[1], zfa[2], 0.f);
    if (act_b) zbuf[ib] = make_float4(zfb[0], zfb[1], zfb[2], 0.f);
    if (!act_a) { gama[0] = gama[1] = gama[2] = gama[3] = 0.f; euc2a = 0.f; }
    if (!act_b) { gamb[0] = gamb[1] = gamb[2] = gamb[3] = 0.f; euc2b = 0.f; }

    // block reduction of 41 moment values (pair pre-summed in-thread)
    int rlane = threadIdx.x & 63;
    int wid = threadIdx.x >> 6;

#define REDUCE_STORE(T, VAL) { float _v = (VAL);                          \
        _v += __shfl_down(_v, 32); _v += __shfl_down(_v, 16);             \
        _v += __shfl_down(_v, 8);  _v += __shfl_down(_v, 4);              \
        _v += __shfl_down(_v, 2);  _v += __shfl_down(_v, 1);              \
        if (rlane == 0) sPart[wid][T] = _v; }

#pragma unroll
    for (int k = 0; k < 4; ++k) REDUCE_STORE(k, gama[k] + gamb[k]);
#pragma unroll
    for (int k = 0; k < 4; ++k) {
#pragma unroll
        for (int d = 0; d < 3; ++d)
            REDUCE_STORE(4 + k * 3 + d, gama[k] * zfa[d] + gamb[k] * zfb[d]);
    }
#pragma unroll
    for (int k = 0; k < 4; ++k) {
        REDUCE_STORE(16 + k * 6 + 0, gama[k]*zfa[0]*zfa[0] + gamb[k]*zfb[0]*zfb[0]);
        REDUCE_STORE(16 + k * 6 + 1, gama[k]*zfa[0]*zfa[1] + gamb[k]*zfb[0]*zfb[1]);
        REDUCE_STORE(16 + k * 6 + 2, gama[k]*zfa[0]*zfa[2] + gamb[k]*zfb[0]*zfb[2]);
        REDUCE_STORE(16 + k * 6 + 3, gama[k]*zfa[1]*zfa[1] + gamb[k]*zfb[1]*zfb[1]);
        REDUCE_STORE(16 + k * 6 + 4, gama[k]*zfa[1]*zfa[2] + gamb[k]*zfb[1]*zfb[2]);
        REDUCE_STORE(16 + k * 6 + 5, gama[k]*zfa[2]*zfa[2] + gamb[k]*zfb[2]*zfb[2]);
    }
    REDUCE_STORE(40, euc2a + euc2b);
#undef REDUCE_STORE

    __syncthreads();
    if (threadIdx.x < 41) {
        double s = (double)sPart[0][threadIdx.x] + (double)sPart[1][threadIdx.x]
                 + (double)sPart[2][threadIdx.x] + (double)sPart[3][threadIdx.x];
        double* accs = acc + (size_t)(blockIdx.x & 7) * 48;
        unsafeAtomicAdd(&accs[threadIdx.x], s);
    }
}

__global__ void gmm_kernel(double* __restrict__ acc, float* __restrict__ P) {
    if (threadIdx.x != 0 || blockIdx.x != 0) return;
    for (int j = 0; j < 42; ++j) {
        double s = acc[j];
        for (int c = 1; c < 8; ++c) s += acc[c * 48 + j];
        acc[j] = s;
    }
    double M[6] = {0, 0, 0, 0, 0, 0}, bv[3] = {0, 0, 0}, A = 0.0, loss3 = 0.0;
    const double TWO_PI = 6.283185307179586;
    for (int k = 0; k < 4; ++k) {
        double g = acc[k];
        double phi = g / (double)NSAMP;
        double mu0 = acc[4 + k * 3 + 0] / g;
        double mu1 = acc[4 + k * 3 + 1] / g;
        double mu2 = acc[4 + k * 3 + 2] / g;
        double S00 = acc[16 + k * 6 + 0] / g - mu0 * mu0;
        double S01 = acc[16 + k * 6 + 1] / g - mu0 * mu1;
        double S02 = acc[16 + k * 6 + 2] / g - mu0 * mu2;
        double S11 = acc[16 + k * 6 + 3] / g - mu1 * mu1;
        double S12 = acc[16 + k * 6 + 4] / g - mu1 * mu2;
        double S22 = acc[16 + k * 6 + 5] / g - mu2 * mu2;
        double c00 = S11 * S22 - S12 * S12;
        double c01 = S02 * S12 - S01 * S22;
        double c02 = S01 * S12 - S02 * S11;
        double det = S00 * c00 + S01 * c01 + S02 * c02;
        double id = 1.0 / det;
        double I00 = c00 * id, I01 = c01 * id, I02 = c02 * id;
        double I11 = (S00 * S22 - S02 * S02) * id;
        double I12 = (S01 * S02 - S00 * S12) * id;
        double I22 = (S00 * S11 - S01 * S01) * id;
        M[0] += I00; M[1] += I01; M[2] += I02; M[3] += I11; M[4] += I12; M[5] += I22;
        double b0 = I00 * mu0 + I01 * mu1 + I02 * mu2;
        double b1 = I01 * mu0 + I11 * mu1 + I12 * mu2;
        double b2 = I02 * mu0 + I12 * mu1 + I22 * mu2;
        bv[0] += b0; bv[1] += b1; bv[2] += b2;
        double quad = mu0 * b0 + mu1 * b1 + mu2 * b2;
        A += -log(phi) + 0.5 * log(TWO_PI * TWO_PI * TWO_PI * det) + 0.5 * quad;
        loss3 += 1e-4 * (1.0 / S00 + 1.0 / S11 + 1.0 / S22);
    }
    P[0] = (float)M[0]; P[1] = (float)M[1]; P[2] = (float)M[2];
    P[3] = (float)M[3]; P[4] = (float)M[4]; P[5] = (float)M[5];
    P[6] = (float)bv[0]; P[7] = (float)bv[1]; P[8] = (float)bv[2];
    P[9] = (float)A;
    acc[42] = acc[40] / (double)NSAMP + loss3;   // loss1 + loss3
}

__global__ __launch_bounds__(256) void energy_kernel(const float4* __restrict__ zbuf,
                                                     const float* __restrict__ P,
                                                     double* __restrict__ acc,
                                                     unsigned* __restrict__ cnt,
                                                     float* __restrict__ out) {
    int i = blockIdx.x * 256 + threadIdx.x;
    float e = 0.f;
    if (i < NSAMP) {
        float4 z4 = zbuf[i];
        float z0 = z4.x, z1 = z4.y, z2 = z4.z;
        float q = P[0] * z0 * z0 + P[3] * z1 * z1 + P[5] * z2 * z2
                + 2.f * (P[1] * z0 * z1 + P[2] * z0 * z2 + P[4] * z1 * z2);
        e = P[9] + 0.5f * q - (P[6] * z0 + P[7] * z1 + P[8] * z2);
        out[i] = e;
    }
    float s = e;
    s += __shfl_down(s, 32); s += __shfl_down(s, 16); s += __shfl_down(s, 8);
    s += __shfl_down(s, 4);  s += __shfl_down(s, 2);  s += __shfl_down(s, 1);
    __shared__ float sE[4];
    if ((threadIdx.x & 63) == 0) sE[threadIdx.x >> 6] = s;
    __syncthreads();
    if (threadIdx.x == 0) {
        double t = (double)sE[0] + (double)sE[1] + (double)sE[2] + (double)sE[3];
        double* accs = acc + (size_t)(blockIdx.x & 7) * 48;
        unsafeAtomicAdd(&accs[41], t);
        __threadfence();
        unsigned old = atomicAdd(cnt, 1u);
        if (old == (unsigned)(NBLK - 1)) {
            double tot = 0.0;
            for (int c = 0; c < 8; ++c)
                tot += unsafeAtomicAdd(&acc[c * 48 + 41], 0.0);
            out[NSAMP] = (float)(acc[42] + 0.01 * tot / (double)NSAMP);
        }
    }
}

extern "C" void kernel_launch(void* const* d_in, const int* in_sizes, int n_in,
                              void* d_out, int out_size, void* d_ws, size_t ws_size,
                              hipStream_t stream) {
    const float* x1  = (const float*)d_in[0];
    const float* ew1 = (const float*)d_in[1];
    const float* eb1 = (const float*)d_in[2];
    const float* ew2 = (const float*)d_in[3];
    const float* eb2 = (const float*)d_in[4];
    const float* ew3 = (const float*)d_in[5];
    const float* eb3 = (const float*)d_in[6];
    const float* dw1 = (const float*)d_in[7];
    const float* db1 = (const float*)d_in[8];
    const float* dw2 = (const float*)d_in[9];
    const float* db2 = (const float*)d_in[10];
    const float* dw3 = (const float*)d_in[11];
    const float* db3 = (const float*)d_in[12];
    const float* tw1 = (const float*)d_in[13];
    const float* tb1 = (const float*)d_in[14];
    const float* tw2 = (const float*)d_in[15];
    const float* tb2 = (const float*)d_in[16];
    float* out = (float*)d_out;
    char* ws = (char*)d_ws;
    double* acc   = (double*)ws;                 // 8 copies x 48 doubles
    unsigned* cnt = (unsigned*)(ws + 3072);
    float* P    = (float*)(ws + 3584);
    float* Gm   = (float*)(ws + 4096);
    float* gv   = (float*)(ws + 5120);
    float* bb   = (float*)(ws + 5184);
    float4* zb  = (float4*)(ws + 8192);

    hipMemsetAsync(d_ws, 0, 3584, stream);
    prep_kernel<<<1, 256, 0, stream>>>(dw3, db3, Gm, gv, bb);
    pass1_kernel<<<NBLKP, 256, 0, stream>>>(x1, ew1, eb1, ew2, eb2, ew3, eb3,
                                            dw1, db1, dw2, db2, dw3, db3,
                                            tw1, tb1, tw2, tb2, Gm, gv, bb, acc, zb);
    gmm_kernel<<<1, 64, 0, stream>>>(acc, P);
    energy_kernel<<<NBLK, 256, 0, stream>>>(zb, P, acc, cnt, out);
}